// Round 20
// baseline (314.569 us; speedup 1.0000x reference)
//
#include <hip/hip_runtime.h>
#include <hip/hip_bf16.h>
#include <math.h>

#define NN 512

typedef __attribute__((ext_vector_type(8))) short short8;
typedef __attribute__((ext_vector_type(4))) float f32x4;

__device__ __forceinline__ float selu_f(float x) {
    const float sc = 1.0507009873554805f, al = 1.6732632423543772f;
    return x > 0.f ? sc * x : sc * al * expm1f(x);
}
__device__ __forceinline__ unsigned short f2b(float f) {
    unsigned int u = __float_as_uint(f);
    unsigned int r = (u + 0x7fffu + ((u >> 16) & 1u)) >> 16;
    return (unsigned short)r;
}
__device__ __forceinline__ float b2f(unsigned short h) {
    return __uint_as_float(((unsigned int)h) << 16);
}
__device__ __forceinline__ float ulo(unsigned int u) {
    return __uint_as_float(u << 16);
}
__device__ __forceinline__ float uhi(unsigned int u) {
    return __uint_as_float(u & 0xffff0000u);
}
__device__ __forceinline__ unsigned int pk2(float a, float b) {
    return (unsigned int)f2b(a) | ((unsigned int)f2b(b) << 16);
}
__device__ __forceinline__ void gload16(const void* g, void* l) {
    __builtin_amdgcn_global_load_lds(
        (const __attribute__((address_space(1))) unsigned int*)g,
        (__attribute__((address_space(3))) unsigned int*)l, 16, 0, 0);
}
__device__ __forceinline__ float dpp_xor1(float x) {
    return __int_as_float(__builtin_amdgcn_update_dpp(
        __float_as_int(x), __float_as_int(x), 0xB1, 0xf, 0xf, true));
}
__device__ __forceinline__ float dpp_xor2(float x) {
    return __int_as_float(__builtin_amdgcn_update_dpp(
        __float_as_int(x), __float_as_int(x), 0x4E, 0xf, 0xf, true));
}

// ---------------- graph construction (verified) ----------------

__global__ __launch_bounds__(64) void nodevec2_kernel(
    const float* __restrict__ emb1, const float* __restrict__ lw1,
    const float* __restrict__ lb1, float* __restrict__ nv1,
    const float* __restrict__ emb2, const float* __restrict__ lw2,
    const float* __restrict__ lb2, float* __restrict__ nv2) {
    __shared__ float e_s[64];
    __shared__ float lws[64][65];
    int which = blockIdx.x >> 9;
    int i = blockIdx.x & 511, j = threadIdx.x;
    const float* emb = which ? emb2 : emb1;
    const float* lw = which ? lw2 : lw1;
    const float* lb = which ? lb2 : lb1;
    float* nv = which ? nv2 : nv1;
    e_s[j] = emb[i * 64 + j];
    for (int k = j; k < 4096; k += 64) lws[k >> 6][k & 63] = lw[k];
    __syncthreads();
    float acc = lb[j];
    for (int k = 0; k < 64; k++) acc += e_s[k] * lws[j][k];
    nv[i * 64 + j] = tanhf(3.0f * acc);
}

__global__ __launch_bounds__(256) void adjacency_tiled(
    const float* __restrict__ nv1, const float* __restrict__ nv2,
    float* __restrict__ adj) {
    __shared__ float A1[64][64], A2[64][64], B1[64][64], B2[64][64];
    int bv = blockIdx.x >> 3, bw = blockIdx.x & 7;
    int t = threadIdx.x;
    for (int i = t; i < 4096; i += 256) {
        int r = i >> 6, c = i & 63;
        A1[r][c] = nv1[(bv * 64 + r) * 64 + c];
        A2[r][c] = nv2[(bv * 64 + r) * 64 + c];
        B1[r][c] = nv1[(bw * 64 + r) * 64 + c];
        B2[r][c] = nv2[(bw * 64 + r) * 64 + c];
    }
    __syncthreads();
    int tv = (t >> 4) * 4, tw = (t & 15) * 4;
    float acc[4][4];
#pragma unroll
    for (int i = 0; i < 4; i++)
#pragma unroll
        for (int j = 0; j < 4; j++) acc[i][j] = 0.f;
    for (int k = 0; k < 64; k++) {
        float a1[4], a2[4], b1[4], b2[4];
#pragma unroll
        for (int i = 0; i < 4; i++) {
            a1[i] = A1[tv + i][k];
            a2[i] = A2[tv + i][k];
            b1[i] = B1[tw + i][k];
            b2[i] = B2[tw + i][k];
        }
#pragma unroll
        for (int i = 0; i < 4; i++)
#pragma unroll
            for (int j = 0; j < 4; j++)
                acc[i][j] += a1[i] * b2[j] - a2[i] * b1[j];
    }
#pragma unroll
    for (int i = 0; i < 4; i++)
#pragma unroll
        for (int j = 0; j < 4; j++)
            adj[(bv * 64 + tv + i) * NN + bw * 64 + tw + j] =
                selu_f(tanhf(3.0f * acc[i][j]));
}

__global__ __launch_bounds__(256) void topk_kernel(
    float* __restrict__ adj, float* __restrict__ rowsump) {
    __shared__ float orig[512], srt[512];
    __shared__ unsigned char keep[512];
    __shared__ float red[256];
    int v = blockIdx.x, t = threadIdx.x;
    orig[t] = adj[v * NN + t];
    orig[t + 256] = adj[v * NN + t + 256];
    srt[t] = orig[t];
    srt[t + 256] = orig[t + 256];
    __syncthreads();
    for (int k = 2; k <= 512; k <<= 1) {
        for (int j = k >> 1; j > 0; j >>= 1) {
            for (int pass = 0; pass < 2; ++pass) {
                int i = t + pass * 256;
                int ixj = i ^ j;
                if (ixj > i) {
                    bool up = ((i & k) == 0);
                    float a = srt[i], b = srt[ixj];
                    if ((a > b) == up) { srt[i] = b; srt[ixj] = a; }
                }
            }
            __syncthreads();
        }
    }
    float thr = srt[256];
    if (t == 0) {
        int g = 0;
        for (int i = 0; i < 512; i++) if (srt[i] > thr) g++;
        int quota = 256 - g;
        for (int w = 0; w < 512; w++) {
            float x = orig[w];
            bool kp = false;
            if (x > thr) kp = true;
            else if (x == thr && quota > 0) { kp = true; quota--; }
            keep[w] = kp ? 1 : 0;
        }
    }
    __syncthreads();
    float part = 0.f;
    for (int pass = 0; pass < 2; pass++) {
        int w = t + pass * 256;
        float val = keep[w] ? orig[w] : 0.0f;
        adj[v * NN + w] = val;
        part += val;
    }
    red[t] = part;
    __syncthreads();
    if (t < 128) red[t] += red[t + 128];
    __syncthreads();
    if (t < 64) {
        float x = red[t] + red[t + 64];
        for (int m = 32; m; m >>= 1) x += __shfl_xor(x, m, 64);
        if (t == 0) rowsump[v] = x + 1.0f;
    }
}

__global__ __launch_bounds__(256) void colsum_part(
    const float* __restrict__ adp, float* __restrict__ part) {
    int b = blockIdx.x, w = threadIdx.x;
    float s0 = 0.f, s1 = 0.f;
    for (int r = 0; r < 32; r++) {
        s0 += adp[(b * 32 + r) * 512 + w];
        s1 += adp[(b * 32 + r) * 512 + w + 256];
    }
    part[b * 512 + w] = s0;
    part[b * 512 + w + 256] = s1;
}
__global__ __launch_bounds__(512) void colsum_red(
    const float* __restrict__ part, float* __restrict__ colsum) {
    int w = threadIdx.x;
    float s = 0.f;
    for (int b = 0; b < 16; b++) s += part[b * 512 + w];
    colsum[w] = s;
}

__global__ __launch_bounds__(256) void normalize_kernel(
    const float* __restrict__ adp, const float* __restrict__ rowsump,
    const float* __restrict__ colsum, unsigned short* __restrict__ a1T,
    unsigned short* __restrict__ a2T) {
    int w = blockIdx.x;
    for (int v = threadIdx.x; v < NN; v += 256) {
        float d = (v == w) ? 1.0f : 0.0f;
        float f1 = (adp[v * NN + w] + d) / rowsump[v];
        float f2 = (adp[w * NN + v] + d) / (colsum[v] + 1.0f);
        unsigned short h1 = f2b(f1), h2 = f2b(f2);
        a1T[w * 1024 + v] = h1;
        a1T[w * 1024 + 512 + v] = f2b(f1 - b2f(h1));
        a2T[w * 1024 + v] = h2;
        a2T[w * 1024 + 512 + v] = f2b(f2 - b2f(h2));
    }
}

// ---------------- basis (x0-only; e-basis cancels in LN#1) ----------------

__global__ __launch_bounds__(256) void build_basis0(
    const float* __restrict__ x, unsigned int* __restrict__ U32) {
    int r = blockIdx.x;
    int n = r >> 6, l = r & 63;
    int t = threadIdx.x;
    float x0v = x[(n * 512 + 2 * t) * 64 + l];
    float x1v = x[(n * 512 + 2 * t + 1) * 64 + l];
    unsigned short h0 = f2b(x0v), h1 = f2b(x1v);
    U32[(size_t)r * 512 + t] = (unsigned int)h0 | ((unsigned int)h1 << 16);
    U32[(size_t)r * 512 + 256 + t] = pk2(x0v - b2f(h0), x1v - b2f(h1));
}

__global__ __launch_bounds__(256, 2) void prop_dualS(
    const unsigned short* __restrict__ src, const unsigned short* __restrict__ B1m,
    const unsigned short* __restrict__ B2m, unsigned short* __restrict__ dst1,
    unsigned short* __restrict__ dst2) {
    __shared__ __align__(16) short At[128 * 64];
    __shared__ __align__(16) short Bt1[64 * 64];
    __shared__ __align__(16) short Bt2[64 * 64];
    int t = threadIdx.x;
    int lane = t & 63;
    int wid = t >> 6;
    int wm = wid >> 1, wn = wid & 1;
    int j0 = blockIdx.x << 7;
    int w0 = blockIdx.y << 6;
    f32x4 acc1[4][2], acc2[4][2];
#pragma unroll
    for (int m = 0; m < 4; m++)
#pragma unroll
        for (int n = 0; n < 2; n++) {
            acc1[m][n] = (f32x4)0.f;
            acc2[m][n] = (f32x4)0.f;
        }
    int l15 = lane & 15;
    int lhi = lane >> 4;
    int rsw = l15 & 7;
    for (int tk = 0; tk < 24; tk++) {
        int kk = tk << 6;
        int ca = (kk < 1024) ? kk : (kk - 1024);
        int cb = (kk < 512) ? kk : (kk - 512);
#pragma unroll
        for (int it = 0; it < 4; it++) {
            int slot = it * 256 + t;
            int r = slot >> 3, sl = slot & 7;
            int so = (sl ^ (r & 7)) << 3;
            gload16(src + (size_t)(j0 + r) * 1024 + ca + so, &At[slot * 8]);
        }
#pragma unroll
        for (int it = 0; it < 2; it++) {
            int slot = it * 256 + t;
            int r = slot >> 3, sl = slot & 7;
            int so = (sl ^ (r & 7)) << 3;
            gload16(B1m + (w0 + r) * 1024 + cb + so, &Bt1[slot * 8]);
            gload16(B2m + (w0 + r) * 1024 + cb + so, &Bt2[slot * 8]);
        }
        __syncthreads();
#pragma unroll
        for (int kh = 0; kh < 2; kh++) {
            int soff = ((kh * 4 + lhi) ^ rsw) << 3;
            short8 a[4], b1[2], b2[2];
#pragma unroll
            for (int m = 0; m < 4; m++)
                a[m] = *(const short8*)&At[(wm * 64 + m * 16 + l15) * 64 + soff];
#pragma unroll
            for (int n = 0; n < 2; n++) {
                b1[n] = *(const short8*)&Bt1[(wn * 32 + n * 16 + l15) * 64 + soff];
                b2[n] = *(const short8*)&Bt2[(wn * 32 + n * 16 + l15) * 64 + soff];
            }
#pragma unroll
            for (int m = 0; m < 4; m++)
#pragma unroll
                for (int n = 0; n < 2; n++) {
                    acc1[m][n] = __builtin_amdgcn_mfma_f32_16x16x32_bf16(
                        a[m], b1[n], acc1[m][n], 0, 0, 0);
                    acc2[m][n] = __builtin_amdgcn_mfma_f32_16x16x32_bf16(
                        a[m], b2[n], acc2[m][n], 0, 0, 0);
                }
        }
        __syncthreads();
    }
#pragma unroll
    for (int m = 0; m < 4; m++) {
#pragma unroll
        for (int n = 0; n < 2; n++) {
#pragma unroll
            for (int r = 0; r < 4; r++) {
                size_t row = j0 + wm * 64 + m * 16 + lhi * 4 + r;
                int col = w0 + wn * 32 + n * 16 + l15;
                size_t ih = row * 1024 + col;
                float f1 = acc1[m][n][r];
                float f2 = acc2[m][n][r];
                unsigned short p1 = f2b(f1), p2 = f2b(f2);
                dst1[ih] = p1;
                dst1[ih + 512] = f2b(f1 - b2f(p1));
                dst2[ih] = p2;
                dst2[ih + 512] = f2b(f2 - b2f(p2));
            }
        }
    }
}

__global__ __launch_bounds__(256, 2) void prop_one(
    const unsigned short* __restrict__ srcA, const unsigned short* __restrict__ Ba,
    unsigned short* __restrict__ dstA, const unsigned short* __restrict__ srcB,
    const unsigned short* __restrict__ Bb, unsigned short* __restrict__ dstB,
    int blocksA) {
    __shared__ __align__(16) short At[128 * 64];
    __shared__ __align__(16) short Bt[64 * 64];
    bool first = (int)blockIdx.x < blocksA;
    const unsigned short* src = first ? srcA : srcB;
    const unsigned short* Bm = first ? Ba : Bb;
    unsigned short* dst = first ? dstA : dstB;
    int bx = first ? blockIdx.x : (blockIdx.x - blocksA);
    int t = threadIdx.x;
    int lane = t & 63;
    int wid = t >> 6;
    int wm = wid >> 1, wn = wid & 1;
    int j0 = bx << 7;
    int w0 = blockIdx.y << 6;
    f32x4 acc[4][2];
#pragma unroll
    for (int m = 0; m < 4; m++)
#pragma unroll
        for (int n = 0; n < 2; n++) acc[m][n] = (f32x4)0.f;
    int l15 = lane & 15;
    int lhi = lane >> 4;
    int rsw = l15 & 7;
    for (int tk = 0; tk < 24; tk++) {
        int kk = tk << 6;
        int ca = (kk < 1024) ? kk : (kk - 1024);
        int cb = (kk < 512) ? kk : (kk - 512);
#pragma unroll
        for (int it = 0; it < 4; it++) {
            int slot = it * 256 + t;
            int r = slot >> 3, sl = slot & 7;
            int so = (sl ^ (r & 7)) << 3;
            gload16(src + (size_t)(j0 + r) * 1024 + ca + so, &At[slot * 8]);
        }
#pragma unroll
        for (int it = 0; it < 2; it++) {
            int slot = it * 256 + t;
            int r = slot >> 3, sl = slot & 7;
            int so = (sl ^ (r & 7)) << 3;
            gload16(Bm + (w0 + r) * 1024 + cb + so, &Bt[slot * 8]);
        }
        __syncthreads();
#pragma unroll
        for (int kh = 0; kh < 2; kh++) {
            int soff = ((kh * 4 + lhi) ^ rsw) << 3;
            short8 a[4], b[2];
#pragma unroll
            for (int m = 0; m < 4; m++)
                a[m] = *(const short8*)&At[(wm * 64 + m * 16 + l15) * 64 + soff];
#pragma unroll
            for (int n = 0; n < 2; n++)
                b[n] = *(const short8*)&Bt[(wn * 32 + n * 16 + l15) * 64 + soff];
#pragma unroll
            for (int m = 0; m < 4; m++)
#pragma unroll
                for (int n = 0; n < 2; n++)
                    acc[m][n] = __builtin_amdgcn_mfma_f32_16x16x32_bf16(
                        a[m], b[n], acc[m][n], 0, 0, 0);
        }
        __syncthreads();
    }
#pragma unroll
    for (int m = 0; m < 4; m++) {
#pragma unroll
        for (int n = 0; n < 2; n++) {
#pragma unroll
            for (int r = 0; r < 4; r++) {
                size_t row = j0 + wm * 64 + m * 16 + lhi * 4 + r;
                int col = w0 + wn * 32 + n * 16 + l15;
                size_t ih = row * 1024 + col;
                float f = acc[m][n][r];
                unsigned short p = f2b(f);
                dst[ih] = p;
                dst[ih + 512] = f2b(f - b2f(p));
            }
        }
    }
}

// coefficient algebra (verified).
__global__ __launch_bounds__(64) void coeff_kernel(
    const float* __restrict__ sw, const float* __restrict__ sb,
    const float* __restrict__ g1w, const float* __restrict__ g1b,
    const float* __restrict__ g2w, const float* __restrict__ g2b,
    float* __restrict__ g2out) {
    __shared__ float g1s[32][10];
    int o = threadIdx.x;
    if (o < 32) {
        float r[10];
#pragma unroll
        for (int b = 0; b < 10; b++) r[b] = 0.f;
        for (int c = 0; c < 32; c++) {
            float w10 = g1w[o * 96 + c], w11 = g1w[o * 96 + 32 + c],
                  w12 = g1w[o * 96 + 64 + c];
            float w20 = g2w[o * 96 + c], w21 = g2w[o * 96 + 32 + c],
                  w22 = g2w[o * 96 + 64 + c];
            float O0 = w10 + w20 + 0.05f * (w11 + w12 + w21 + w22);
            float O1a = 0.95f * w11 + 0.0475f * w12;
            float O2a = 0.9025f * w12;
            float O1b = 0.95f * w21 + 0.0475f * w22;
            float O2b = 0.9025f * w22;
            float swc = sw[c], sbc = sb[c];
            r[0] += O0 * swc;  r[1] += O0 * sbc;
            r[2] += O1a * swc; r[3] += O1a * sbc;
            r[4] += O2a * swc; r[5] += O2a * sbc;
            r[6] += O1b * swc; r[7] += O1b * sbc;
            r[8] += O2b * swc; r[9] += O2b * sbc;
        }
        r[1] += g1b[o] + g2b[o];
#pragma unroll
        for (int b = 0; b < 10; b++) g1s[o][b] = r[b];
    }
    __syncthreads();
    if (o < 32) {
        float g2r[50];
#pragma unroll
        for (int b = 0; b < 50; b++) g2r[b] = 0.f;
        const float* W1 = g1w + 32 * 96;
        const float* W2 = g2w + 32 * 96;
        for (int c = 0; c < 32; c++) {
            float w10 = W1[o * 96 + c], w11 = W1[o * 96 + 32 + c],
                  w12 = W1[o * 96 + 64 + c];
            float w20 = W2[o * 96 + c], w21 = W2[o * 96 + 32 + c],
                  w22 = W2[o * 96 + 64 + c];
            float O0 = w10 + w20 + 0.05f * (w11 + w12 + w21 + w22);
            float O1a = 0.95f * w11 + 0.0475f * w12;
            float O2a = 0.9025f * w12;
            float O1b = 0.95f * w21 + 0.0475f * w22;
            float O2b = 0.9025f * w22;
#pragma unroll
            for (int b1 = 0; b1 < 10; b1++) {
                float g = g1s[c][b1];
                g2r[b1] += O0 * g;
                g2r[10 + b1] += O1a * g;
                g2r[20 + b1] += O2a * g;
                g2r[30 + b1] += O1b * g;
                g2r[40 + b1] += O2b * g;
            }
        }
        g2r[1] += g1b[32 + o] + g2b[32 + o];
#pragma unroll
        for (int b = 0; b < 50; b++) g2out[b * 32 + o] = g2r[b];
    }
}

// reconstruct over 25 x0-basis tensors (verified).
__global__ __launch_bounds__(256) void reconstruct25(
    const unsigned int* __restrict__ U32, const float* __restrict__ g2,
    unsigned int* __restrict__ hC) {
    int r = blockIdx.x;
    int n = r >> 6, l = r & 63;
    int t = threadIdx.x;
    float a0[32], a1[32];
#pragma unroll
    for (int o = 0; o < 32; o++) { a0[o] = 0.f; a1[o] = 0.f; }
    for (int b = 0; b < 25; b++) {
        unsigned int hi = U32[(size_t)(b * 256 + r) * 512 + t];
        unsigned int lo = U32[(size_t)(b * 256 + r) * 512 + 256 + t];
        float u0 = ulo(hi) + ulo(lo);
        float u1 = uhi(hi) + uhi(lo);
        int old = (b / 5) * 10 + (b % 5) * 2;
        const float* gb = g2 + old * 32;
#pragma unroll
        for (int o = 0; o < 32; o++) {
            a0[o] += gb[o] * u0;
            a1[o] += gb[o] * u1;
        }
    }
#pragma unroll
    for (int o = 0; o < 32; o++) {
        size_t j = (size_t)((n * 32 + o) * 64 + l);
        unsigned short p0 = f2b(a0[o]), p1 = f2b(a1[o]);
        hC[j * 512 + t] = (unsigned int)p0 | ((unsigned int)p1 << 16);
        hC[j * 512 + 256 + t] = pk2(a0[o] - b2f(p0), a1[o] - b2f(p1));
    }
}

// LayerNorm#1 + transpose (verified).
__global__ __launch_bounds__(256) void lnt_kernel(
    const unsigned short* __restrict__ h, const float* __restrict__ lw,
    const float* __restrict__ lb, unsigned int* __restrict__ ht) {
    __shared__ float th[64][65];
    __shared__ unsigned int tt[64][65];
    __shared__ float p1s[4][64], p2s[4][64], ms[64], is[64];
    int b = blockIdx.x;
    int c = b & 31, vb = (b >> 5) & 7, n = b >> 8;
    int t = threadIdx.x;
#pragma unroll
    for (int half = 0; half < 2; half++) {
        int s = half * 256 + t;
        int l = s >> 3, q = s & 7;
        const unsigned short* p =
            h + (size_t)((n * 32 + c) * 64 + l) * 1024 + vb * 64 + q * 8;
        short8 hiv = *(const short8*)p;
        short8 lov = *(const short8*)(p + 512);
#pragma unroll
        for (int i = 0; i < 8; i++)
            th[l][q * 8 + i] =
                b2f((unsigned short)hiv[i]) + b2f((unsigned short)lov[i]);
    }
    __syncthreads();
    {
        int v = t & 63, g = t >> 6;
        float s = 0.f, sq = 0.f;
#pragma unroll
        for (int i = 0; i < 16; i++) {
            float f = th[g * 16 + i][v];
            s += f;
            sq += f * f;
        }
        p1s[g][v] = s;
        p2s[g][v] = sq;
    }
    __syncthreads();
    if (t < 64) {
        float s = p1s[0][t] + p1s[1][t] + p1s[2][t] + p1s[3][t];
        float sq = p2s[0][t] + p2s[1][t] + p2s[2][t] + p2s[3][t];
        float m = s * (1.f / 64.f);
        float var = fmaxf(sq * (1.f / 64.f) - m * m, 0.f);
        ms[t] = m;
        is[t] = 1.f / sqrtf(var + 1e-12f);
    }
    __syncthreads();
    {
        int v = t & 63, g = t >> 6;
        float m = ms[v], inv = is[v];
#pragma unroll
        for (int i = 0; i < 16; i++) {
            int l = g * 16 + i;
            float f = lw[l] * (th[l][v] - m) * inv + lb[l];
            unsigned short hi = f2b(f);
            tt[v][l] = (unsigned int)hi | ((unsigned int)f2b(f - b2f(hi)) << 16);
        }
    }
    __syncthreads();
    {
        int vr = t >> 2, ch = t & 3;
        unsigned int* dstp =
            ht + (size_t)(n * 512 + vb * 64 + vr) * 2048 + c * 64 + ch * 16;
#pragma unroll
        for (int i = 0; i < 4; i++) {
            uint4 val;
            val.x = tt[vr][ch * 16 + i * 4 + 0];
            val.y = tt[vr][ch * 16 + i * 4 + 1];
            val.z = tt[vr][ch * 16 + i * 4 + 2];
            val.w = tt[vr][ch * 16 + i * 4 + 3];
            *(uint4*)(dstp + i * 4) = val;
        }
    }
}

// fused end stage v7: weights bf16-PACKED in LDS (halves the ds_read_b128
// count that dominates this kernel: 1536 -> 768 per wave).
__global__ __launch_bounds__(256, 2) void end_fused7(
    const unsigned int* __restrict__ ht, const float* __restrict__ w1,
    const float* __restrict__ b1, const float* __restrict__ w2,
    const float* __restrict__ b2, const float* __restrict__ lw,
    const float* __restrict__ lb, float* __restrict__ out) {
    __shared__ unsigned int w1p[64 * 16];  // [o1][cq] bf16-pair, 4 KB
    __shared__ unsigned int w2p[64 * 32];  // [o2][oq] bf16-pair, 8 KB
    __shared__ float b1s[64], b2s[64], lws[64], lbs[64];
    int t = threadIdx.x;
    for (int i = t; i < 1024; i += 256) {
        int o1 = i >> 4, cq = i & 15;
        w1p[i] = pk2(w1[o1 * 32 + 2 * cq], w1[o1 * 32 + 2 * cq + 1]);
    }
    for (int i = t; i < 2048; i += 256) {
        int o2 = i >> 5, oq = i & 31;
        w2p[i] = pk2(w2[o2 * 64 + 2 * oq], w2[o2 * 64 + 2 * oq + 1]);
    }
    if (t < 64) {
        b1s[t] = b1[t];
        b2s[t] = b2[t];
        lws[t] = lw[t];
        lbs[t] = lb[t];
    }
    __syncthreads();
    int wid = t >> 6, lane = t & 63;
    int gw = blockIdx.x * 4 + wid;
    int n = gw >> 9, v = gw & 511;
    const unsigned int* row = ht + (size_t)(n * 512 + v) * 2048;
    float hvf[32];
#pragma unroll
    for (int c = 0; c < 32; c++) {
        unsigned int u = row[c * 64 + lane];
        hvf[c] = ulo(u) + uhi(u);
    }
    unsigned int e1p[32];
#pragma unroll
    for (int op = 0; op < 32; op++) {
        float a0 = b1s[2 * op], a1 = b1s[2 * op + 1];
#pragma unroll
        for (int cb = 0; cb < 4; cb++) {
            uint4 wa = *(const uint4*)&w1p[(2 * op) * 16 + cb * 4];
            uint4 wb = *(const uint4*)&w1p[(2 * op + 1) * 16 + cb * 4];
            int c0 = cb * 8;
            a0 += ulo(wa.x) * hvf[c0] + uhi(wa.x) * hvf[c0 + 1] +
                  ulo(wa.y) * hvf[c0 + 2] + uhi(wa.y) * hvf[c0 + 3] +
                  ulo(wa.z) * hvf[c0 + 4] + uhi(wa.z) * hvf[c0 + 5] +
                  ulo(wa.w) * hvf[c0 + 6] + uhi(wa.w) * hvf[c0 + 7];
            a1 += ulo(wb.x) * hvf[c0] + uhi(wb.x) * hvf[c0 + 1] +
                  ulo(wb.y) * hvf[c0 + 2] + uhi(wb.y) * hvf[c0 + 3] +
                  ulo(wb.z) * hvf[c0 + 4] + uhi(wb.z) * hvf[c0 + 5] +
                  ulo(wb.w) * hvf[c0 + 6] + uhi(wb.w) * hvf[c0 + 7];
        }
        e1p[op] = pk2(selu_f(a0), selu_f(a1));
    }
    float lwl = lws[lane], lbl = lbs[lane];
    float accout = 0.f;
    for (int o2 = 0; o2 < 64; o2++) {
        float pa = 0.f, pb = 0.f;
#pragma unroll
        for (int ob = 0; ob < 8; ob++) {
            uint4 wv = *(const uint4*)&w2p[o2 * 32 + ob * 4];
            unsigned int u0 = e1p[ob * 4];
            unsigned int u1 = e1p[ob * 4 + 1];
            unsigned int u2 = e1p[ob * 4 + 2];
            unsigned int u3 = e1p[ob * 4 + 3];
            pa += ulo(wv.x) * ulo(u0) + uhi(wv.x) * uhi(u0) +
                  ulo(wv.y) * ulo(u1) + uhi(wv.y) * uhi(u1);
            pb += ulo(wv.z) * ulo(u2) + uhi(wv.z) * uhi(u2) +
                  ulo(wv.w) * ulo(u3) + uhi(wv.w) * uhi(u3);
        }
        float e2 = b2s[o2] + (pa + pb);
        float sA = e2, sB = e2 * e2;
        sA += dpp_xor1(sA);
        sB += dpp_xor1(sB);
        sA += dpp_xor2(sA);
        sB += dpp_xor2(sB);
#pragma unroll
        for (int m = 4; m < 64; m <<= 1) {
            sA += __shfl_xor(sA, m, 64);
            sB += __shfl_xor(sB, m, 64);
        }
        float mean = sA * (1.f / 64.f);
        float var = fmaxf(sB * (1.f / 64.f) - mean * mean, 0.f);
        float inv = 1.f / sqrtf(var + 1e-12f);
        accout += lwl * (e2 - mean) * inv + lbl;
    }
    out[(n * 64 + lane) * 512 + v] = accout;
}

// ---------------- launch ----------------

extern "C" void kernel_launch(void* const* d_in, const int* in_sizes, int n_in,
                              void* d_out, int out_size, void* d_ws,
                              size_t ws_size, hipStream_t stream) {
    const float* x = (const float*)d_in[0];
    const float* emb1 = (const float*)d_in[1];
    const float* emb2 = (const float*)d_in[2];
    const float* lin1_w = (const float*)d_in[3];
    const float* lin1_b = (const float*)d_in[4];
    const float* lin2_w = (const float*)d_in[5];
    const float* lin2_b = (const float*)d_in[6];
    const float* start_w = (const float*)d_in[7];
    const float* start_b = (const float*)d_in[8];
    const float* g1_w = (const float*)d_in[9];
    const float* g1_b = (const float*)d_in[10];
    const float* g2_w = (const float*)d_in[11];
    const float* g2_b = (const float*)d_in[12];
    const float* ln_w = (const float*)d_in[13];
    const float* ln_b = (const float*)d_in[14];
    const float* end1_w = (const float*)d_in[15];
    const float* end1_b = (const float*)d_in[16];
    const float* end2_w = (const float*)d_in[17];
    const float* end2_b = (const float*)d_in[18];
    float* out = (float*)d_out;

    char* ws = (char*)d_ws;
    unsigned short* a1T = (unsigned short*)(ws + 0);
    unsigned short* a2T = (unsigned short*)(ws + 1048576);
    unsigned short* U = (unsigned short*)(ws + 2097152);
    unsigned short* hC = (unsigned short*)(ws + 18874368);
    unsigned int* ht = (unsigned int*)(ws + 35651584);
    float* g2T = (float*)(ws + 52428800);
    char* scr = ws + 53477376;
    float* nv1 = (float*)(scr + 0);
    float* nv2 = (float*)(scr + 131072);
    float* adp = (float*)(scr + 262144);
    float* rowsump = (float*)(scr + 1310720);
    float* colsum = (float*)(scr + 1312768);
    float* cspart = (float*)(scr + 1314816);

    const size_t TS = 262144;

    build_basis0<<<256, 256, 0, stream>>>(x, (unsigned int*)U);

    nodevec2_kernel<<<1024, 64, 0, stream>>>(emb1, lin1_w, lin1_b, nv1, emb2,
                                             lin2_w, lin2_b, nv2);
    adjacency_tiled<<<64, 256, 0, stream>>>(nv1, nv2, adp);
    topk_kernel<<<512, 256, 0, stream>>>(adp, rowsump);
    colsum_part<<<16, 256, 0, stream>>>(adp, cspart);
    colsum_red<<<1, 512, 0, stream>>>(cspart, colsum);
    normalize_kernel<<<512, 256, 0, stream>>>(adp, rowsump, colsum, a1T, a2T);

    prop_dualS<<<dim3(2, 8), 256, 0, stream>>>(U, a1T, a2T, U + 1 * TS,
                                               U + 3 * TS);
    prop_one<<<dim3(4, 8), 256, 0, stream>>>(U + 1 * TS, a1T, U + 2 * TS,
                                             U + 3 * TS, a2T, U + 4 * TS, 2);
    prop_dualS<<<dim3(10, 8), 256, 0, stream>>>(U, a1T, a2T, U + 5 * TS,
                                                U + 15 * TS);
    prop_one<<<dim3(20, 8), 256, 0, stream>>>(U + 5 * TS, a1T, U + 10 * TS,
                                              U + 15 * TS, a2T, U + 20 * TS,
                                              10);

    coeff_kernel<<<1, 64, 0, stream>>>(start_w, start_b, g1_w, g1_b, g2_w,
                                       g2_b, g2T);
    reconstruct25<<<256, 256, 0, stream>>>((const unsigned int*)U, g2T,
                                           (unsigned int*)hC);

    lnt_kernel<<<1024, 256, 0, stream>>>(hC, ln_w, ln_b, ht);
    end_fused7<<<512, 256, 0, stream>>>((const unsigned int*)ht, end1_w,
                                        end1_b, end2_w, end2_b, ln_w, ln_b,
                                        out);
}

// Round 21
// 298.202 us; speedup vs baseline: 1.0549x; 1.0549x over previous
//
#include <hip/hip_runtime.h>
#include <hip/hip_bf16.h>
#include <math.h>

#define NN 512

typedef __attribute__((ext_vector_type(8))) short short8;
typedef __attribute__((ext_vector_type(4))) float f32x4;

__device__ __forceinline__ float selu_f(float x) {
    const float sc = 1.0507009873554805f, al = 1.6732632423543772f;
    return x > 0.f ? sc * x : sc * al * expm1f(x);
}
__device__ __forceinline__ unsigned short f2b(float f) {
    unsigned int u = __float_as_uint(f);
    unsigned int r = (u + 0x7fffu + ((u >> 16) & 1u)) >> 16;
    return (unsigned short)r;
}
__device__ __forceinline__ float b2f(unsigned short h) {
    return __uint_as_float(((unsigned int)h) << 16);
}
__device__ __forceinline__ float ulo(unsigned int u) {
    return __uint_as_float(u << 16);
}
__device__ __forceinline__ float uhi(unsigned int u) {
    return __uint_as_float(u & 0xffff0000u);
}
__device__ __forceinline__ unsigned int pk2(float a, float b) {
    return (unsigned int)f2b(a) | ((unsigned int)f2b(b) << 16);
}
__device__ __forceinline__ void gload16(const void* g, void* l) {
    __builtin_amdgcn_global_load_lds(
        (const __attribute__((address_space(1))) unsigned int*)g,
        (__attribute__((address_space(3))) unsigned int*)l, 16, 0, 0);
}
__device__ __forceinline__ float dpp_xor1(float x) {
    return __int_as_float(__builtin_amdgcn_update_dpp(
        __float_as_int(x), __float_as_int(x), 0xB1, 0xf, 0xf, true));
}
__device__ __forceinline__ float dpp_xor2(float x) {
    return __int_as_float(__builtin_amdgcn_update_dpp(
        __float_as_int(x), __float_as_int(x), 0x4E, 0xf, 0xf, true));
}

// ---------------- graph construction (verified) ----------------

__global__ __launch_bounds__(64) void nodevec2_kernel(
    const float* __restrict__ emb1, const float* __restrict__ lw1,
    const float* __restrict__ lb1, float* __restrict__ nv1,
    const float* __restrict__ emb2, const float* __restrict__ lw2,
    const float* __restrict__ lb2, float* __restrict__ nv2) {
    __shared__ float e_s[64];
    __shared__ float lws[64][65];
    int which = blockIdx.x >> 9;
    int i = blockIdx.x & 511, j = threadIdx.x;
    const float* emb = which ? emb2 : emb1;
    const float* lw = which ? lw2 : lw1;
    const float* lb = which ? lb2 : lb1;
    float* nv = which ? nv2 : nv1;
    e_s[j] = emb[i * 64 + j];
    for (int k = j; k < 4096; k += 64) lws[k >> 6][k & 63] = lw[k];
    __syncthreads();
    float acc = lb[j];
    for (int k = 0; k < 64; k++) acc += e_s[k] * lws[j][k];
    nv[i * 64 + j] = tanhf(3.0f * acc);
}

__global__ __launch_bounds__(256) void adjacency_tiled(
    const float* __restrict__ nv1, const float* __restrict__ nv2,
    float* __restrict__ adj) {
    __shared__ float A1[64][64], A2[64][64], B1[64][64], B2[64][64];
    int bv = blockIdx.x >> 3, bw = blockIdx.x & 7;
    int t = threadIdx.x;
    for (int i = t; i < 4096; i += 256) {
        int r = i >> 6, c = i & 63;
        A1[r][c] = nv1[(bv * 64 + r) * 64 + c];
        A2[r][c] = nv2[(bv * 64 + r) * 64 + c];
        B1[r][c] = nv1[(bw * 64 + r) * 64 + c];
        B2[r][c] = nv2[(bw * 64 + r) * 64 + c];
    }
    __syncthreads();
    int tv = (t >> 4) * 4, tw = (t & 15) * 4;
    float acc[4][4];
#pragma unroll
    for (int i = 0; i < 4; i++)
#pragma unroll
        for (int j = 0; j < 4; j++) acc[i][j] = 0.f;
    for (int k = 0; k < 64; k++) {
        float a1[4], a2[4], b1[4], b2[4];
#pragma unroll
        for (int i = 0; i < 4; i++) {
            a1[i] = A1[tv + i][k];
            a2[i] = A2[tv + i][k];
            b1[i] = B1[tw + i][k];
            b2[i] = B2[tw + i][k];
        }
#pragma unroll
        for (int i = 0; i < 4; i++)
#pragma unroll
            for (int j = 0; j < 4; j++)
                acc[i][j] += a1[i] * b2[j] - a2[i] * b1[j];
    }
#pragma unroll
    for (int i = 0; i < 4; i++)
#pragma unroll
        for (int j = 0; j < 4; j++)
            adj[(bv * 64 + tv + i) * NN + bw * 64 + tw + j] =
                selu_f(tanhf(3.0f * acc[i][j]));
}

__global__ __launch_bounds__(256) void topk_kernel(
    float* __restrict__ adj, float* __restrict__ rowsump) {
    __shared__ float orig[512], srt[512];
    __shared__ unsigned char keep[512];
    __shared__ float red[256];
    int v = blockIdx.x, t = threadIdx.x;
    orig[t] = adj[v * NN + t];
    orig[t + 256] = adj[v * NN + t + 256];
    srt[t] = orig[t];
    srt[t + 256] = orig[t + 256];
    __syncthreads();
    for (int k = 2; k <= 512; k <<= 1) {
        for (int j = k >> 1; j > 0; j >>= 1) {
            for (int pass = 0; pass < 2; ++pass) {
                int i = t + pass * 256;
                int ixj = i ^ j;
                if (ixj > i) {
                    bool up = ((i & k) == 0);
                    float a = srt[i], b = srt[ixj];
                    if ((a > b) == up) { srt[i] = b; srt[ixj] = a; }
                }
            }
            __syncthreads();
        }
    }
    float thr = srt[256];
    if (t == 0) {
        int g = 0;
        for (int i = 0; i < 512; i++) if (srt[i] > thr) g++;
        int quota = 256 - g;
        for (int w = 0; w < 512; w++) {
            float x = orig[w];
            bool kp = false;
            if (x > thr) kp = true;
            else if (x == thr && quota > 0) { kp = true; quota--; }
            keep[w] = kp ? 1 : 0;
        }
    }
    __syncthreads();
    float part = 0.f;
    for (int pass = 0; pass < 2; pass++) {
        int w = t + pass * 256;
        float val = keep[w] ? orig[w] : 0.0f;
        adj[v * NN + w] = val;
        part += val;
    }
    red[t] = part;
    __syncthreads();
    if (t < 128) red[t] += red[t + 128];
    __syncthreads();
    if (t < 64) {
        float x = red[t] + red[t + 64];
        for (int m = 32; m; m >>= 1) x += __shfl_xor(x, m, 64);
        if (t == 0) rowsump[v] = x + 1.0f;
    }
}

__global__ __launch_bounds__(256) void colsum_part(
    const float* __restrict__ adp, float* __restrict__ part) {
    int b = blockIdx.x, w = threadIdx.x;
    float s0 = 0.f, s1 = 0.f;
    for (int r = 0; r < 32; r++) {
        s0 += adp[(b * 32 + r) * 512 + w];
        s1 += adp[(b * 32 + r) * 512 + w + 256];
    }
    part[b * 512 + w] = s0;
    part[b * 512 + w + 256] = s1;
}
__global__ __launch_bounds__(512) void colsum_red(
    const float* __restrict__ part, float* __restrict__ colsum) {
    int w = threadIdx.x;
    float s = 0.f;
    for (int b = 0; b < 16; b++) s += part[b * 512 + w];
    colsum[w] = s;
}

__global__ __launch_bounds__(256) void normalize_kernel(
    const float* __restrict__ adp, const float* __restrict__ rowsump,
    const float* __restrict__ colsum, unsigned short* __restrict__ a1T,
    unsigned short* __restrict__ a2T) {
    int w = blockIdx.x;
    for (int v = threadIdx.x; v < NN; v += 256) {
        float d = (v == w) ? 1.0f : 0.0f;
        float f1 = (adp[v * NN + w] + d) / rowsump[v];
        float f2 = (adp[w * NN + v] + d) / (colsum[v] + 1.0f);
        unsigned short h1 = f2b(f1), h2 = f2b(f2);
        a1T[w * 1024 + v] = h1;
        a1T[w * 1024 + 512 + v] = f2b(f1 - b2f(h1));
        a2T[w * 1024 + v] = h2;
        a2T[w * 1024 + 512 + v] = f2b(f2 - b2f(h2));
    }
}

// ---------------- basis (x0-only; e-basis cancels in LN#1) ----------------
// Ux: 25 tensors [256 rows=(n*64+l)][1024] hi/lo. Layout:
// 0=x0 1=A1x0 2=A1^2x0 3=A2x0 4=A2^2x0 ; 5+k=A1*U[k] ; 10+k=A1*U[5+k] ;
// 15+k=A2*U[k] ; 20+k=A2*U[15+k]   (k=0..4)

__global__ __launch_bounds__(256) void build_basis0(
    const float* __restrict__ x, unsigned int* __restrict__ U32) {
    int r = blockIdx.x;
    int n = r >> 6, l = r & 63;
    int t = threadIdx.x;
    float x0v = x[(n * 512 + 2 * t) * 64 + l];
    float x1v = x[(n * 512 + 2 * t + 1) * 64 + l];
    unsigned short h0 = f2b(x0v), h1 = f2b(x1v);
    U32[(size_t)r * 512 + t] = (unsigned int)h0 | ((unsigned int)h1 << 16);
    U32[(size_t)r * 512 + 256 + t] = pk2(x0v - b2f(h0), x1v - b2f(h1));
}

__global__ __launch_bounds__(256, 2) void prop_dualS(
    const unsigned short* __restrict__ src, const unsigned short* __restrict__ B1m,
    const unsigned short* __restrict__ B2m, unsigned short* __restrict__ dst1,
    unsigned short* __restrict__ dst2) {
    __shared__ __align__(16) short At[128 * 64];
    __shared__ __align__(16) short Bt1[64 * 64];
    __shared__ __align__(16) short Bt2[64 * 64];
    int t = threadIdx.x;
    int lane = t & 63;
    int wid = t >> 6;
    int wm = wid >> 1, wn = wid & 1;
    int j0 = blockIdx.x << 7;
    int w0 = blockIdx.y << 6;
    f32x4 acc1[4][2], acc2[4][2];
#pragma unroll
    for (int m = 0; m < 4; m++)
#pragma unroll
        for (int n = 0; n < 2; n++) {
            acc1[m][n] = (f32x4)0.f;
            acc2[m][n] = (f32x4)0.f;
        }
    int l15 = lane & 15;
    int lhi = lane >> 4;
    int rsw = l15 & 7;
    for (int tk = 0; tk < 24; tk++) {
        int kk = tk << 6;
        int ca = (kk < 1024) ? kk : (kk - 1024);
        int cb = (kk < 512) ? kk : (kk - 512);
#pragma unroll
        for (int it = 0; it < 4; it++) {
            int slot = it * 256 + t;
            int r = slot >> 3, sl = slot & 7;
            int so = (sl ^ (r & 7)) << 3;
            gload16(src + (size_t)(j0 + r) * 1024 + ca + so, &At[slot * 8]);
        }
#pragma unroll
        for (int it = 0; it < 2; it++) {
            int slot = it * 256 + t;
            int r = slot >> 3, sl = slot & 7;
            int so = (sl ^ (r & 7)) << 3;
            gload16(B1m + (w0 + r) * 1024 + cb + so, &Bt1[slot * 8]);
            gload16(B2m + (w0 + r) * 1024 + cb + so, &Bt2[slot * 8]);
        }
        __syncthreads();
#pragma unroll
        for (int kh = 0; kh < 2; kh++) {
            int soff = ((kh * 4 + lhi) ^ rsw) << 3;
            short8 a[4], b1[2], b2[2];
#pragma unroll
            for (int m = 0; m < 4; m++)
                a[m] = *(const short8*)&At[(wm * 64 + m * 16 + l15) * 64 + soff];
#pragma unroll
            for (int n = 0; n < 2; n++) {
                b1[n] = *(const short8*)&Bt1[(wn * 32 + n * 16 + l15) * 64 + soff];
                b2[n] = *(const short8*)&Bt2[(wn * 32 + n * 16 + l15) * 64 + soff];
            }
#pragma unroll
            for (int m = 0; m < 4; m++)
#pragma unroll
                for (int n = 0; n < 2; n++) {
                    acc1[m][n] = __builtin_amdgcn_mfma_f32_16x16x32_bf16(
                        a[m], b1[n], acc1[m][n], 0, 0, 0);
                    acc2[m][n] = __builtin_amdgcn_mfma_f32_16x16x32_bf16(
                        a[m], b2[n], acc2[m][n], 0, 0, 0);
                }
        }
        __syncthreads();
    }
#pragma unroll
    for (int m = 0; m < 4; m++) {
#pragma unroll
        for (int n = 0; n < 2; n++) {
#pragma unroll
            for (int r = 0; r < 4; r++) {
                size_t row = j0 + wm * 64 + m * 16 + lhi * 4 + r;
                int col = w0 + wn * 32 + n * 16 + l15;
                size_t ih = row * 1024 + col;
                float f1 = acc1[m][n][r];
                float f2 = acc2[m][n][r];
                unsigned short p1 = f2b(f1), p2 = f2b(f2);
                dst1[ih] = p1;
                dst1[ih + 512] = f2b(f1 - b2f(p1));
                dst2[ih] = p2;
                dst2[ih + 512] = f2b(f2 - b2f(p2));
            }
        }
    }
}

__global__ __launch_bounds__(256, 2) void prop_one(
    const unsigned short* __restrict__ srcA, const unsigned short* __restrict__ Ba,
    unsigned short* __restrict__ dstA, const unsigned short* __restrict__ srcB,
    const unsigned short* __restrict__ Bb, unsigned short* __restrict__ dstB,
    int blocksA) {
    __shared__ __align__(16) short At[128 * 64];
    __shared__ __align__(16) short Bt[64 * 64];
    bool first = (int)blockIdx.x < blocksA;
    const unsigned short* src = first ? srcA : srcB;
    const unsigned short* Bm = first ? Ba : Bb;
    unsigned short* dst = first ? dstA : dstB;
    int bx = first ? blockIdx.x : (blockIdx.x - blocksA);
    int t = threadIdx.x;
    int lane = t & 63;
    int wid = t >> 6;
    int wm = wid >> 1, wn = wid & 1;
    int j0 = bx << 7;
    int w0 = blockIdx.y << 6;
    f32x4 acc[4][2];
#pragma unroll
    for (int m = 0; m < 4; m++)
#pragma unroll
        for (int n = 0; n < 2; n++) acc[m][n] = (f32x4)0.f;
    int l15 = lane & 15;
    int lhi = lane >> 4;
    int rsw = l15 & 7;
    for (int tk = 0; tk < 24; tk++) {
        int kk = tk << 6;
        int ca = (kk < 1024) ? kk : (kk - 1024);
        int cb = (kk < 512) ? kk : (kk - 512);
#pragma unroll
        for (int it = 0; it < 4; it++) {
            int slot = it * 256 + t;
            int r = slot >> 3, sl = slot & 7;
            int so = (sl ^ (r & 7)) << 3;
            gload16(src + (size_t)(j0 + r) * 1024 + ca + so, &At[slot * 8]);
        }
#pragma unroll
        for (int it = 0; it < 2; it++) {
            int slot = it * 256 + t;
            int r = slot >> 3, sl = slot & 7;
            int so = (sl ^ (r & 7)) << 3;
            gload16(Bm + (w0 + r) * 1024 + cb + so, &Bt[slot * 8]);
        }
        __syncthreads();
#pragma unroll
        for (int kh = 0; kh < 2; kh++) {
            int soff = ((kh * 4 + lhi) ^ rsw) << 3;
            short8 a[4], b[2];
#pragma unroll
            for (int m = 0; m < 4; m++)
                a[m] = *(const short8*)&At[(wm * 64 + m * 16 + l15) * 64 + soff];
#pragma unroll
            for (int n = 0; n < 2; n++)
                b[n] = *(const short8*)&Bt[(wn * 32 + n * 16 + l15) * 64 + soff];
#pragma unroll
            for (int m = 0; m < 4; m++)
#pragma unroll
                for (int n = 0; n < 2; n++)
                    acc[m][n] = __builtin_amdgcn_mfma_f32_16x16x32_bf16(
                        a[m], b[n], acc[m][n], 0, 0, 0);
        }
        __syncthreads();
    }
#pragma unroll
    for (int m = 0; m < 4; m++) {
#pragma unroll
        for (int n = 0; n < 2; n++) {
#pragma unroll
            for (int r = 0; r < 4; r++) {
                size_t row = j0 + wm * 64 + m * 16 + lhi * 4 + r;
                int col = w0 + wn * 32 + n * 16 + l15;
                size_t ih = row * 1024 + col;
                float f = acc[m][n][r];
                unsigned short p = f2b(f);
                dst[ih] = p;
                dst[ih + 512] = f2b(f - b2f(p));
            }
        }
    }
}

// reconstruct over 25 x0-basis tensors with coefficient algebra computed
// IN-BLOCK (removes the separate coeff_kernel dispatch + g2T round-trip).
// Coefficient math is bit-identical to the verified coeff_kernel.
__global__ __launch_bounds__(256) void reconstruct25c(
    const unsigned int* __restrict__ U32, const float* __restrict__ sw,
    const float* __restrict__ sb, const float* __restrict__ g1w,
    const float* __restrict__ g1b, const float* __restrict__ g2w,
    const float* __restrict__ g2b, unsigned int* __restrict__ hC) {
    __shared__ float g1s[32][10];
    __shared__ float g2s[50 * 32];
    int t = threadIdx.x;
    if (t < 32) {
        int o = t;
        float rr[10];
#pragma unroll
        for (int b = 0; b < 10; b++) rr[b] = 0.f;
        for (int c = 0; c < 32; c++) {
            float w10 = g1w[o * 96 + c], w11 = g1w[o * 96 + 32 + c],
                  w12 = g1w[o * 96 + 64 + c];
            float w20 = g2w[o * 96 + c], w21 = g2w[o * 96 + 32 + c],
                  w22 = g2w[o * 96 + 64 + c];
            float O0 = w10 + w20 + 0.05f * (w11 + w12 + w21 + w22);
            float O1a = 0.95f * w11 + 0.0475f * w12;
            float O2a = 0.9025f * w12;
            float O1b = 0.95f * w21 + 0.0475f * w22;
            float O2b = 0.9025f * w22;
            float swc = sw[c], sbc = sb[c];
            rr[0] += O0 * swc;  rr[1] += O0 * sbc;
            rr[2] += O1a * swc; rr[3] += O1a * sbc;
            rr[4] += O2a * swc; rr[5] += O2a * sbc;
            rr[6] += O1b * swc; rr[7] += O1b * sbc;
            rr[8] += O2b * swc; rr[9] += O2b * sbc;
        }
        rr[1] += g1b[o] + g2b[o];
#pragma unroll
        for (int b = 0; b < 10; b++) g1s[o][b] = rr[b];
    }
    __syncthreads();
    if (t < 32) {
        int o = t;
        float g2r[50];
#pragma unroll
        for (int b = 0; b < 50; b++) g2r[b] = 0.f;
        const float* W1 = g1w + 32 * 96;
        const float* W2 = g2w + 32 * 96;
        for (int c = 0; c < 32; c++) {
            float w10 = W1[o * 96 + c], w11 = W1[o * 96 + 32 + c],
                  w12 = W1[o * 96 + 64 + c];
            float w20 = W2[o * 96 + c], w21 = W2[o * 96 + 32 + c],
                  w22 = W2[o * 96 + 64 + c];
            float O0 = w10 + w20 + 0.05f * (w11 + w12 + w21 + w22);
            float O1a = 0.95f * w11 + 0.0475f * w12;
            float O2a = 0.9025f * w12;
            float O1b = 0.95f * w21 + 0.0475f * w22;
            float O2b = 0.9025f * w22;
#pragma unroll
            for (int b1 = 0; b1 < 10; b1++) {
                float g = g1s[c][b1];
                g2r[b1] += O0 * g;
                g2r[10 + b1] += O1a * g;
                g2r[20 + b1] += O2a * g;
                g2r[30 + b1] += O1b * g;
                g2r[40 + b1] += O2b * g;
            }
        }
        g2r[1] += g1b[32 + o] + g2b[32 + o];
#pragma unroll
        for (int b = 0; b < 50; b++) g2s[b * 32 + o] = g2r[b];
    }
    __syncthreads();
    int r = blockIdx.x;
    int n = r >> 6, l = r & 63;
    float a0[32], a1[32];
#pragma unroll
    for (int o = 0; o < 32; o++) { a0[o] = 0.f; a1[o] = 0.f; }
    for (int b = 0; b < 25; b++) {
        unsigned int hi = U32[(size_t)(b * 256 + r) * 512 + t];
        unsigned int lo = U32[(size_t)(b * 256 + r) * 512 + 256 + t];
        float u0 = ulo(hi) + ulo(lo);
        float u1 = uhi(hi) + uhi(lo);
        int old = (b / 5) * 10 + (b % 5) * 2;
        const float* gb = g2s + old * 32;
#pragma unroll
        for (int o = 0; o < 32; o++) {
            a0[o] += gb[o] * u0;
            a1[o] += gb[o] * u1;
        }
    }
#pragma unroll
    for (int o = 0; o < 32; o++) {
        size_t j = (size_t)((n * 32 + o) * 64 + l);
        unsigned short p0 = f2b(a0[o]), p1 = f2b(a1[o]);
        hC[j * 512 + t] = (unsigned int)p0 | ((unsigned int)p1 << 16);
        hC[j * 512 + 256 + t] = pk2(a0[o] - b2f(p0), a1[o] - b2f(p1));
    }
}

// LayerNorm#1 + transpose (verified).
__global__ __launch_bounds__(256) void lnt_kernel(
    const unsigned short* __restrict__ h, const float* __restrict__ lw,
    const float* __restrict__ lb, unsigned int* __restrict__ ht) {
    __shared__ float th[64][65];
    __shared__ unsigned int tt[64][65];
    __shared__ float p1s[4][64], p2s[4][64], ms[64], is[64];
    int b = blockIdx.x;
    int c = b & 31, vb = (b >> 5) & 7, n = b >> 8;
    int t = threadIdx.x;
#pragma unroll
    for (int half = 0; half < 2; half++) {
        int s = half * 256 + t;
        int l = s >> 3, q = s & 7;
        const unsigned short* p =
            h + (size_t)((n * 32 + c) * 64 + l) * 1024 + vb * 64 + q * 8;
        short8 hiv = *(const short8*)p;
        short8 lov = *(const short8*)(p + 512);
#pragma unroll
        for (int i = 0; i < 8; i++)
            th[l][q * 8 + i] =
                b2f((unsigned short)hiv[i]) + b2f((unsigned short)lov[i]);
    }
    __syncthreads();
    {
        int v = t & 63, g = t >> 6;
        float s = 0.f, sq = 0.f;
#pragma unroll
        for (int i = 0; i < 16; i++) {
            float f = th[g * 16 + i][v];
            s += f;
            sq += f * f;
        }
        p1s[g][v] = s;
        p2s[g][v] = sq;
    }
    __syncthreads();
    if (t < 64) {
        float s = p1s[0][t] + p1s[1][t] + p1s[2][t] + p1s[3][t];
        float sq = p2s[0][t] + p2s[1][t] + p2s[2][t] + p2s[3][t];
        float m = s * (1.f / 64.f);
        float var = fmaxf(sq * (1.f / 64.f) - m * m, 0.f);
        ms[t] = m;
        is[t] = 1.f / sqrtf(var + 1e-12f);
    }
    __syncthreads();
    {
        int v = t & 63, g = t >> 6;
        float m = ms[v], inv = is[v];
#pragma unroll
        for (int i = 0; i < 16; i++) {
            int l = g * 16 + i;
            float f = lw[l] * (th[l][v] - m) * inv + lb[l];
            unsigned short hi = f2b(f);
            tt[v][l] = (unsigned int)hi | ((unsigned int)f2b(f - b2f(hi)) << 16);
        }
    }
    __syncthreads();
    {
        int vr = t >> 2, ch = t & 3;
        unsigned int* dstp =
            ht + (size_t)(n * 512 + vb * 64 + vr) * 2048 + c * 64 + ch * 16;
#pragma unroll
        for (int i = 0; i < 4; i++) {
            uint4 val;
            val.x = tt[vr][ch * 16 + i * 4 + 0];
            val.y = tt[vr][ch * 16 + i * 4 + 1];
            val.z = tt[vr][ch * 16 + i * 4 + 2];
            val.w = tt[vr][ch * 16 + i * 4 + 3];
            *(uint4*)(dstp + i * 4) = val;
        }
    }
}

// fused end stage (verified best, 68 us).
__global__ __launch_bounds__(256, 2) void end_fused6(
    const unsigned int* __restrict__ ht, const float* __restrict__ w1,
    const float* __restrict__ b1, const float* __restrict__ w2,
    const float* __restrict__ b2, const float* __restrict__ lw,
    const float* __restrict__ lb, float* __restrict__ out) {
    __shared__ float w1s[64 * 32];
    __shared__ float w2s[64 * 64];
    __shared__ float b1s[64], b2s[64], lws[64], lbs[64];
    int t = threadIdx.x;
    for (int i = t; i < 2048; i += 256) w1s[i] = w1[i];
    for (int i = t; i < 4096; i += 256) w2s[i] = w2[i];
    if (t < 64) {
        b1s[t] = b1[t];
        b2s[t] = b2[t];
        lws[t] = lw[t];
        lbs[t] = lb[t];
    }
    __syncthreads();
    int wid = t >> 6, lane = t & 63;
    int gw = blockIdx.x * 4 + wid;
    int n = gw >> 9, v = gw & 511;
    const unsigned int* row = ht + (size_t)(n * 512 + v) * 2048;
    float hvf[32];
#pragma unroll
    for (int c = 0; c < 32; c++) {
        unsigned int u = row[c * 64 + lane];
        hvf[c] = ulo(u) + uhi(u);
    }
    unsigned int e1p[32];
#pragma unroll
    for (int op = 0; op < 32; op++) {
        float a0 = b1s[2 * op], a1 = b1s[2 * op + 1];
#pragma unroll
        for (int cq = 0; cq < 8; cq++) {
            float4 wa = *(const float4*)&w1s[(2 * op) * 32 + cq * 4];
            float4 wb = *(const float4*)&w1s[(2 * op + 1) * 32 + cq * 4];
            a0 += wa.x * hvf[cq * 4] + wa.y * hvf[cq * 4 + 1] +
                  wa.z * hvf[cq * 4 + 2] + wa.w * hvf[cq * 4 + 3];
            a1 += wb.x * hvf[cq * 4] + wb.y * hvf[cq * 4 + 1] +
                  wb.z * hvf[cq * 4 + 2] + wb.w * hvf[cq * 4 + 3];
        }
        e1p[op] = pk2(selu_f(a0), selu_f(a1));
    }
    float lwl = lws[lane], lbl = lbs[lane];
    float accout = 0.f;
    for (int o2 = 0; o2 < 64; o2++) {
        float pa = 0.f, pb = 0.f;
#pragma unroll
        for (int oq = 0; oq < 16; oq++) {
            float4 wv = *(const float4*)&w2s[o2 * 64 + oq * 4];
            unsigned int u0 = e1p[oq * 2];
            unsigned int u1 = e1p[oq * 2 + 1];
            pa += wv.x * ulo(u0) + wv.z * ulo(u1);
            pb += wv.y * uhi(u0) + wv.w * uhi(u1);
        }
        float e2 = b2s[o2] + (pa + pb);
        float sA = e2, sB = e2 * e2;
        sA += dpp_xor1(sA);
        sB += dpp_xor1(sB);
        sA += dpp_xor2(sA);
        sB += dpp_xor2(sB);
#pragma unroll
        for (int m = 4; m < 64; m <<= 1) {
            sA += __shfl_xor(sA, m, 64);
            sB += __shfl_xor(sB, m, 64);
        }
        float mean = sA * (1.f / 64.f);
        float var = fmaxf(sB * (1.f / 64.f) - mean * mean, 0.f);
        float inv = 1.f / sqrtf(var + 1e-12f);
        accout += lwl * (e2 - mean) * inv + lbl;
    }
    out[(n * 64 + lane) * 512 + v] = accout;
}

// ---------------- launch ----------------

extern "C" void kernel_launch(void* const* d_in, const int* in_sizes, int n_in,
                              void* d_out, int out_size, void* d_ws,
                              size_t ws_size, hipStream_t stream) {
    const float* x = (const float*)d_in[0];
    const float* emb1 = (const float*)d_in[1];
    const float* emb2 = (const float*)d_in[2];
    const float* lin1_w = (const float*)d_in[3];
    const float* lin1_b = (const float*)d_in[4];
    const float* lin2_w = (const float*)d_in[5];
    const float* lin2_b = (const float*)d_in[6];
    const float* start_w = (const float*)d_in[7];
    const float* start_b = (const float*)d_in[8];
    const float* g1_w = (const float*)d_in[9];
    const float* g1_b = (const float*)d_in[10];
    const float* g2_w = (const float*)d_in[11];
    const float* g2_b = (const float*)d_in[12];
    const float* ln_w = (const float*)d_in[13];
    const float* ln_b = (const float*)d_in[14];
    const float* end1_w = (const float*)d_in[15];
    const float* end1_b = (const float*)d_in[16];
    const float* end2_w = (const float*)d_in[17];
    const float* end2_b = (const float*)d_in[18];
    float* out = (float*)d_out;

    char* ws = (char*)d_ws;
    unsigned short* a1T = (unsigned short*)(ws + 0);
    unsigned short* a2T = (unsigned short*)(ws + 1048576);
    unsigned short* U = (unsigned short*)(ws + 2097152);
    unsigned short* hC = (unsigned short*)(ws + 18874368);
    unsigned int* ht = (unsigned int*)(ws + 35651584);
    char* scr = ws + 53477376;
    float* nv1 = (float*)(scr + 0);
    float* nv2 = (float*)(scr + 131072);
    float* adp = (float*)(scr + 262144);
    float* rowsump = (float*)(scr + 1310720);
    float* colsum = (float*)(scr + 1312768);
    float* cspart = (float*)(scr + 1314816);

    const size_t TS = 262144;

    build_basis0<<<256, 256, 0, stream>>>(x, (unsigned int*)U);

    nodevec2_kernel<<<1024, 64, 0, stream>>>(emb1, lin1_w, lin1_b, nv1, emb2,
                                             lin2_w, lin2_b, nv2);
    adjacency_tiled<<<64, 256, 0, stream>>>(nv1, nv2, adp);
    topk_kernel<<<512, 256, 0, stream>>>(adp, rowsump);
    colsum_part<<<16, 256, 0, stream>>>(adp, cspart);
    colsum_red<<<1, 512, 0, stream>>>(cspart, colsum);
    normalize_kernel<<<512, 256, 0, stream>>>(adp, rowsump, colsum, a1T, a2T);

    prop_dualS<<<dim3(2, 8), 256, 0, stream>>>(U, a1T, a2T, U + 1 * TS,
                                               U + 3 * TS);
    prop_one<<<dim3(4, 8), 256, 0, stream>>>(U + 1 * TS, a1T, U + 2 * TS,
                                             U + 3 * TS, a2T, U + 4 * TS, 2);
    prop_dualS<<<dim3(10, 8), 256, 0, stream>>>(U, a1T, a2T, U + 5 * TS,
                                                U + 15 * TS);
    prop_one<<<dim3(20, 8), 256, 0, stream>>>(U + 5 * TS, a1T, U + 10 * TS,
                                              U + 15 * TS, a2T, U + 20 * TS,
                                              10);

    reconstruct25c<<<256, 256, 0, stream>>>((const unsigned int*)U, start_w,
                                            start_b, g1_w, g1_b, g2_w, g2_b,
                                            (unsigned int*)hC);

    lnt_kernel<<<1024, 256, 0, stream>>>(hC, ln_w, ln_b, ht);
    end_fused6<<<512, 256, 0, stream>>>((const unsigned int*)ht, end1_w,
                                        end1_b, end2_w, end2_b, ln_w, ln_b,
                                        out);
}